// Round 11
// baseline (3829.225 us; speedup 1.0000x reference)
//
#include <hip/hip_runtime.h>

// RNN: out[n,t,:] = tanh(x[n,t,:]@Wx + b + h_{t-1}@Wh),  h_{-1} = h0
// N=64, T=512, D=512, H=1024, fp32 in/out.
// Round 11: R10 geometry (2 row-halves x 32 col-tiles, 2 pipelined 16-row
// phases) + R8 split-bf16 numerics + R8 tag-in-data protocol, PLUS two
// codegen-hazard fixes in the poll loop:
//  (a) "=&v" early-clobber on poll loads (retry was re-issuing from
//      clobbered address registers under high VGPR pressure),
//  (b) sched_barrier(0) + opaque "+v" touch after s_waitcnt vmcnt(0)
//      (rule-18: tag-check VALU must not hoist past the waitcnt).

#define NN 64
#define TT 512
#define DD 512
#define HH 1024

typedef unsigned int  u32;
typedef unsigned short u16;

typedef __attribute__((ext_vector_type(8))) short bf16x8;
typedef __attribute__((ext_vector_type(4))) float f32x4;
typedef __attribute__((ext_vector_type(4))) u32   u32x4;
typedef __attribute__((ext_vector_type(2))) u32   u32x2;

#define MFMA16(a, b, c) __builtin_amdgcn_mfma_f32_16x16x32_bf16((a), (b), (c), 0, 0, 0)

__device__ __forceinline__ u32 bf16r(float f) {          // RTNE fp32->bf16 (bits)
    u32 u = __float_as_uint(f);
    return (u + 0x7fffu + ((u >> 16) & 1u)) >> 16;
}
__device__ __forceinline__ float bf16tof(u32 h) { return __uint_as_float(h << 16); }
__device__ __forceinline__ void split2(float f, u32& hi, u32& lo) {
    hi = bf16r(f);
    lo = bf16r(f - bf16tof(hi));
}

// ---- system-scope (sc0 sc1) ops; no "memory" clobbers ----------------------
__device__ __forceinline__ u32x4 ld16_sys(const u32* p) {   // issue-only
    u32x4 v;
    asm volatile("global_load_dwordx4 %0, %1, off sc0 sc1" : "=&v"(v) : "v"(p));
    return v;
}
__device__ __forceinline__ void st8_sys(u32* p, u32 v0, u32 v1) {
    u32x2 v = {v0, v1};
    asm volatile("global_store_dwordx2 %0, %1, off sc0 sc1" :: "v"(p), "v"(v));
}
__device__ __forceinline__ void wait_vm0() {
    asm volatile("s_waitcnt vmcnt(0)");
}

__device__ __forceinline__ float fast_tanh(float x) {
    float e = __expf(2.0f * x);
    return 1.0f - __fdividef(2.0f, e + 1.0f);   // exact +/-1 saturation
}

// ---------------------------------------------------------------------------
// Prep: pack Wx and Wh into MFMA-fragment order (hi/lo bf16); pack h0 with
// tag bit. h buffer: u32 [2 parity][64][1024], value = hi<<16 | lo&0xFFFE | tag.
// h_s lives in buf[s&1] with tag (s>>1)&1;  h_{-1}=h0 -> buf[1], tag 1.
// buf[0] starts with tag bit 1 (stale marker for t=1 readers).
// Fragment layout for 16x16x32: p = ((jt*KB + kb)*64 + lane)*8 + e
//   j = jt*16 + (lane&15),  k = kb*32 + (lane>>4)*8 + e
// ---------------------------------------------------------------------------
__global__ __launch_bounds__(256) void prep_kernel(
    const float* __restrict__ Wx, const float* __restrict__ Wh,
    const float* __restrict__ h0,
    u16* __restrict__ WxPh, u16* __restrict__ WxPl,
    u16* __restrict__ WhPh, u16* __restrict__ WhPl,
    u32* __restrict__ hpk)
{
    const int stride = gridDim.x * 256;
    const int gid = blockIdx.x * 256 + threadIdx.x;

    for (int p = gid; p < 64 * 16 * 64 * 8; p += stride) {   // Wx
        int e = p & 7, l = (p >> 3) & 63, kb = (p >> 9) & 15, jt = p >> 13;
        int j = jt * 16 + (l & 15);
        int k = kb * 32 + ((l >> 4) << 3) + e;
        u32 hi, lo; split2(Wx[k * HH + j], hi, lo);
        WxPh[p] = (u16)hi; WxPl[p] = (u16)lo;
    }
    for (int p = gid; p < 64 * 32 * 64 * 8; p += stride) {   // Wh
        int e = p & 7, l = (p >> 3) & 63, kb = (p >> 9) & 31, jt = p >> 14;
        int j = jt * 16 + (l & 15);
        int k = kb * 32 + ((l >> 4) << 3) + e;
        u32 hi, lo; split2(Wh[k * HH + j], hi, lo);
        WhPh[p] = (u16)hi; WhPl[p] = (u16)lo;
    }
    for (int p = gid; p < NN * HH; p += stride) {            // h0
        u32 hi, lo; split2(h0[p], hi, lo);
        hpk[NN * HH + p] = (hi << 16) | (lo & 0xFFFEu) | 1u; // buf[1], tag 1
        hpk[p] = 1u;                                         // buf[0] stale tag
    }
}

// ---------------------------------------------------------------------------
// Phase 1: out = x@Wx + b   (split-bf16, 128x128 tiles, grid 2048) — proven
// ---------------------------------------------------------------------------
__global__ __launch_bounds__(256) void gemm_kernel(
    const float* __restrict__ x, const float* __restrict__ b,
    const u16* __restrict__ WxPh, const u16* __restrict__ WxPl,
    float* __restrict__ out)
{
    __shared__ __align__(16) u32 ldsA[2][128][20];

    const int tid = threadIdx.x;
    const int bid = blockIdx.x;
    const int w   = tid >> 6;
    const int l   = tid & 63;
    const int wm = w >> 1, wj = w & 1;

    const int m0 = (bid >> 3) * 128;
    const int jb = bid & 7;
    const int j0 = jb * 128;

    f32x4 acc[4][4] = {};
    for (int ks = 0; ks < 16; ++ks) {
        const int k0 = ks * 32;
        #pragma unroll
        for (int it = 0; it < 8; ++it) {
            int idx = it * 256 + tid;
            int m = idx >> 4, kp = idx & 15;
            float2 v = *(const float2*)(x + (m0 + m) * DD + k0 + kp * 2);
            u32 h0b, l0b, h1b, l1b;
            split2(v.x, h0b, l0b);
            split2(v.y, h1b, l1b);
            ldsA[0][m][kp] = h0b | (h1b << 16);
            ldsA[1][m][kp] = l0b | (l1b << 16);
        }
        __syncthreads();

        bf16x8 afh[4], afl[4], bfh[4], bfl[4];
        #pragma unroll
        for (int mt4 = 0; mt4 < 4; ++mt4) {
            int row = wm * 64 + mt4 * 16 + (l & 15);
            int co  = (l >> 4) * 4;
            afh[mt4] = *(const bf16x8*)&ldsA[0][row][co];
            afl[mt4] = *(const bf16x8*)&ldsA[1][row][co];
        }
        #pragma unroll
        for (int jt4 = 0; jt4 < 4; ++jt4) {
            int jtile = jb * 8 + wj * 4 + jt4;
            int off = ((jtile * 16 + ks) * 64 + l) * 8;
            bfh[jt4] = *(const bf16x8*)(WxPh + off);
            bfl[jt4] = *(const bf16x8*)(WxPl + off);
        }
        #pragma unroll
        for (int mt4 = 0; mt4 < 4; ++mt4)
            #pragma unroll
            for (int jt4 = 0; jt4 < 4; ++jt4) {
                acc[mt4][jt4] = MFMA16(afh[mt4], bfh[jt4], acc[mt4][jt4]);
                acc[mt4][jt4] = MFMA16(afh[mt4], bfl[jt4], acc[mt4][jt4]);
                acc[mt4][jt4] = MFMA16(afl[mt4], bfh[jt4], acc[mt4][jt4]);
            }
        __syncthreads();
    }
    #pragma unroll
    for (int jt4 = 0; jt4 < 4; ++jt4) {
        int j = j0 + wj * 64 + jt4 * 16 + (l & 15);
        float bj = b[j];
        #pragma unroll
        for (int mt4 = 0; mt4 < 4; ++mt4)
            #pragma unroll
            for (int r = 0; r < 4; ++r) {
                int m = m0 + wm * 64 + mt4 * 16 + (l >> 4) * 4 + r;
                out[m * HH + j] = acc[mt4][jt4][r] + bj;
            }
    }
}

// ---------------------------------------------------------------------------
// Phase 2: scan. Grid 64 x 256. Block: rh = bid&1 (rows [32rh,+32)),
// cb = bid>>1 (cols [32cb,+32)). Wave w owns k-slice [256w,+256).
// Per step: 2 phases of 16 rows, pipelined. Tag-in-data h exchange.
// ---------------------------------------------------------------------------
__global__ __launch_bounds__(256, 1) void scan_kernel(
    const u16* __restrict__ WhPh, const u16* __restrict__ WhPl,
    u32* __restrict__ hbuf,          // [2][64][1024] packed
    float* __restrict__ out)
{
    __shared__ __align__(16) char ldsWhH[65536];   // 64 frags x 1 KB
    __shared__ __align__(16) char ldsWhL[65536];
    __shared__ float ldsRed[2][4][16][34];         // [phase][wave][row][col]

    const int tid = threadIdx.x;
    const int bid = blockIdx.x;
    const int rh  = bid & 1;
    const int cb  = bid >> 1;
    const int w   = tid >> 6;
    const int l   = tid & 63;

    // ---- stage Wh fragments into LDS (once); frag f=(w*2+jj)*8+i ----
    for (int c = tid; c < 4096; c += 256) {        // 4096 x 16B chunks
        int f = c >> 6, q = c & 63;
        int fw = f >> 4, fj = (f >> 3) & 1, fi = f & 7;
        int src = (((cb * 2 + fj) * 32) + (fw * 8 + fi)) * 512 + q * 8;
        *(u32x4*)(ldsWhH + c * 16) = *(const u32x4*)(WhPh + src);
        *(u32x4*)(ldsWhL + c * 16) = *(const u32x4*)(WhPl + src);
    }
    __syncthreads();

    const int kbase = w * 256 + ((l >> 4) << 3);
    const int rL = tid >> 4;                       // local row 0..15 finalized
    const int c0 = (tid & 15) * 2;                 // col pair within 32
    const int jE = cb * 32 + c0;

    float2 xwv[2];
    xwv[0] = *(const float2*)&out[((32 * rh + rL) * TT) * HH + jE];
    xwv[1] = *(const float2*)&out[((32 * rh + 16 + rL) * TT) * HH + jE];

    for (int t = 0; t < TT; ++t) {
        #pragma unroll
        for (int ph = 0; ph < 2; ++ph) {
            const int nA = 32 * rh + 16 * ph + (l & 15);   // A-frag batch row
            const int nF = 32 * rh + 16 * ph + rL;         // finalized row

            // ---- Wh fragment LDS reads (issued; consumed in MFMA) ----
            u32x4 bh[2][8], bl[2][8];
            #pragma unroll
            for (int jj = 0; jj < 2; ++jj)
                #pragma unroll
                for (int i = 0; i < 8; ++i) {
                    int off = (((w * 2 + jj) * 8 + i) << 10) + (l << 4);
                    bh[jj][i] = *(const u32x4*)(ldsWhH + off);
                    bl[jj][i] = *(const u32x4*)(ldsWhL + off);
                }
            __builtin_amdgcn_sched_barrier(0);

            // ---- poll h_{t-1} (tag-validated data) ----
            const u32 tg = (u32)(((t - 1) >> 1) & 1);      // t=0 -> 1 (h0)
            const u32* hp = hbuf + ((t - 1) & 1) * NN * HH + nA * HH + kbase;

            u32x4 a0[8], a1[8];
            bool ready = false;
            do {
                if (!ready) {
                    #pragma unroll
                    for (int i = 0; i < 8; ++i) {
                        a0[i] = ld16_sys(hp + i * 32);
                        a1[i] = ld16_sys(hp + i * 32 + 4);
                    }
                    wait_vm0();
                    // rule-18 fence: nothing below may hoist above the waitcnt
                    __builtin_amdgcn_sched_barrier(0);
                    #pragma unroll
                    for (int i = 0; i < 8; ++i) {
                        asm volatile("" : "+v"(a0[i]));
                        asm volatile("" : "+v"(a1[i]));
                    }
                    u32 cAnd = ~0u, cOr = 0u;
                    #pragma unroll
                    for (int i = 0; i < 8; ++i) {
                        cAnd &= a0[i][0] & a0[i][1] & a0[i][2] & a0[i][3];
                        cAnd &= a1[i][0] & a1[i][1] & a1[i][2] & a1[i][3];
                        cOr  |= a0[i][0] | a0[i][1] | a0[i][2] | a0[i][3];
                        cOr  |= a1[i][0] | a1[i][1] | a1[i][2] | a1[i][3];
                    }
                    ready = tg ? ((cAnd & 1u) != 0u) : ((cOr & 1u) == 0u);
                }
            } while (__ballot(!ready) != 0ull);
            __builtin_amdgcn_sched_barrier(0);

            // ---- unpack h + MFMA (3 split chains) ----
            f32x4 ahh[2] = {}, ahl[2] = {}, alh[2] = {};
            #pragma unroll
            for (int i = 0; i < 8; ++i) {
                bf16x8 Ah, Al;
                #pragma unroll
                for (int e = 0; e < 4; ++e) {
                    u32 u0 = a0[i][e], u1 = a1[i][e];
                    Ah[e]     = (short)(u0 >> 16);
                    Al[e]     = (short)(u0 & 0xFFFEu);
                    Ah[4 + e] = (short)(u1 >> 16);
                    Al[4 + e] = (short)(u1 & 0xFFFEu);
                }
                #pragma unroll
                for (int jj = 0; jj < 2; ++jj) {
                    bf16x8 Bh = __builtin_bit_cast(bf16x8, bh[jj][i]);
                    bf16x8 Bl = __builtin_bit_cast(bf16x8, bl[jj][i]);
                    ahh[jj] = MFMA16(Ah, Bh, ahh[jj]);
                    ahl[jj] = MFMA16(Ah, Bl, ahl[jj]);
                    alh[jj] = MFMA16(Al, Bh, alh[jj]);
                }
            }

            // ---- cross-wave reduce (phase-buffered, 1 barrier) ----
            {
                int rb = (l >> 4) * 4, cc = l & 15;
                #pragma unroll
                for (int jj = 0; jj < 2; ++jj) {
                    f32x4 s4 = ahh[jj] + ahl[jj] + alh[jj];
                    #pragma unroll
                    for (int e = 0; e < 4; ++e)
                        ldsRed[ph][w][rb + e][jj * 16 + cc] = s4[e];
                }
            }
            __syncthreads();

            float sx = 0.f, sy = 0.f;
            #pragma unroll
            for (int wq = 0; wq < 4; ++wq) {
                float2 v = *(const float2*)&ldsRed[ph][wq][rL][c0];
                sx += v.x; sy += v.y;
            }
            float hv0 = fast_tanh(xwv[ph].x + sx);
            float hv1 = fast_tanh(xwv[ph].y + sy);

            if (t + 1 < TT) {                      // fire-and-forget tagged post
                const u32 tagw = (u32)((t >> 1) & 1);
                u32 hb0, lb0, hb1, lb1;
                split2(hv0, hb0, lb0);
                split2(hv1, hb1, lb1);
                u32 p0 = (hb0 << 16) | (lb0 & 0xFFFEu) | tagw;
                u32 p1 = (hb1 << 16) | (lb1 & 0xFFFEu) | tagw;
                st8_sys(hbuf + (t & 1) * NN * HH + nF * HH + jE, p0, p1);
            }
            *(float2*)&out[(nF * TT + t) * HH + jE] = make_float2(hv0, hv1);
            if (t + 1 < TT)
                xwv[ph] = *(const float2*)&out[(nF * TT + t + 1) * HH + jE];
        }
    }
}

// ---------------------------------------------------------------------------
extern "C" void kernel_launch(void* const* d_in, const int* in_sizes, int n_in,
                              void* d_out, int out_size, void* d_ws, size_t ws_size,
                              hipStream_t stream) {
    const float* x  = (const float*)d_in[0];
    const float* h0 = (const float*)d_in[1];
    const float* Wx = (const float*)d_in[2];
    const float* Wh = (const float*)d_in[3];
    const float* b  = (const float*)d_in[4];
    float* out = (float*)d_out;

    char* ws = (char*)d_ws;
    u16* WxPh = (u16*)(ws);                           // 1 MB
    u16* WxPl = (u16*)(ws + (1u << 20));              // 1 MB
    u16* WhPh = (u16*)(ws + (2u << 20));              // 2 MB
    u16* WhPl = (u16*)(ws + (4u << 20));              // 2 MB
    u32* hbuf = (u32*)(ws + (6u << 20));              // [2][64][1024] u32 = 512 KB

    prep_kernel<<<2048, 256, 0, stream>>>(Wx, Wh, h0, WxPh, WxPl, WhPh, WhPl, hbuf);
    gemm_kernel<<<2048, 256, 0, stream>>>(x, b, WxPh, WxPl, out);
    scan_kernel<<<64, 256, 0, stream>>>(WhPh, WhPl, hbuf, out);
}

// Round 12
// 1557.878 us; speedup vs baseline: 2.4580x; 2.4580x over previous
//
#include <hip/hip_runtime.h>

// RNN: out[n,t,:] = tanh(x[n,t,:]@Wx + b + h_{t-1}@Wh),  h_{-1} = h0
// N=64, T=512, D=512, H=1024, fp32 in/out.
// Round 12: R8 structure (4 groups x 32 col-blocks, Wh in LDS, split-bf16
// 3-chain numerics) + R11 codegen fixes, with:
//  - per-wave monotone flags + single unvalidated h fetch (poll retries are
//    4B/lane instead of 256B/lane -> kills the IC retry-BW term),
//  - h buffer in MFMA A-fragment order (consumer fetch = dense coalesced
//    dwordx4 from a contiguous 16KB region; producer stores stay 8B/thread),
//  - full 16-bit lo on the wire (no tag bit).

#define NN 64
#define TT 512
#define DD 512
#define HH 1024

typedef unsigned int  u32;
typedef unsigned short u16;

typedef __attribute__((ext_vector_type(8))) short bf16x8;
typedef __attribute__((ext_vector_type(4))) float f32x4;
typedef __attribute__((ext_vector_type(4))) u32   u32x4;
typedef __attribute__((ext_vector_type(2))) u32   u32x2;

#define MFMA16(a, b, c) __builtin_amdgcn_mfma_f32_16x16x32_bf16((a), (b), (c), 0, 0, 0)

__device__ __forceinline__ u32 bf16r(float f) {          // RTNE fp32->bf16 (bits)
    u32 u = __float_as_uint(f);
    return (u + 0x7fffu + ((u >> 16) & 1u)) >> 16;
}
__device__ __forceinline__ float bf16tof(u32 h) { return __uint_as_float(h << 16); }
__device__ __forceinline__ void split2(float f, u32& hi, u32& lo) {
    hi = bf16r(f);
    lo = bf16r(f - bf16tof(hi));
}

// ---- system-scope (sc0 sc1) ops; no "memory" clobbers ----------------------
__device__ __forceinline__ u32x4 ld16_sys(const u32* p) {   // issue-only
    u32x4 v;
    asm volatile("global_load_dwordx4 %0, %1, off sc0 sc1" : "=&v"(v) : "v"(p));
    return v;
}
__device__ __forceinline__ void st8_sys(u32* p, u32 v0, u32 v1) {
    u32x2 v = {v0, v1};
    asm volatile("global_store_dwordx2 %0, %1, off sc0 sc1" :: "v"(p), "v"(v));
}
__device__ __forceinline__ void st_flag(u32* p, u32 v) {
    asm volatile("global_store_dword %0, %1, off sc0 sc1" :: "v"(p), "v"(v));
}
__device__ __forceinline__ void wait_vm0() {
    asm volatile("s_waitcnt vmcnt(0)");
}

__device__ __forceinline__ float fast_tanh(float x) {
    float e = __expf(2.0f * x);
    return 1.0f - __fdividef(2.0f, e + 1.0f);   // exact +/-1 saturation
}

// ---------------------------------------------------------------------------
// Prep: Wx/Wh -> MFMA-fragment order (hi/lo bf16); h0 -> fragment-ordered
// packed wire (hi16<<16 | lo16), parity-1 buffer.
// Weight fragment layout (16x16x32): p = ((jt*KB + kb)*64 + lane)*8 + e
//   j = jt*16 + (lane&15),  k = kb*32 + (lane>>4)*8 + e
// h wire layout: hbuf[(par*4+g)*32*512 + kb*512 + lane*8 + e] holds
//   h[n = g*16 + (lane&15), k = kb*32 + (lane>>4)*8 + e]  (A-frag order).
// ---------------------------------------------------------------------------
__global__ __launch_bounds__(256) void prep_kernel(
    const float* __restrict__ Wx, const float* __restrict__ Wh,
    const float* __restrict__ h0,
    u16* __restrict__ WxPh, u16* __restrict__ WxPl,
    u16* __restrict__ WhPh, u16* __restrict__ WhPl,
    u32* __restrict__ hpk)
{
    const int stride = gridDim.x * 256;
    const int gid = blockIdx.x * 256 + threadIdx.x;

    for (int p = gid; p < 64 * 16 * 64 * 8; p += stride) {   // Wx
        int e = p & 7, l = (p >> 3) & 63, kb = (p >> 9) & 15, jt = p >> 13;
        int j = jt * 16 + (l & 15);
        int k = kb * 32 + ((l >> 4) << 3) + e;
        u32 hi, lo; split2(Wx[k * HH + j], hi, lo);
        WxPh[p] = (u16)hi; WxPl[p] = (u16)lo;
    }
    for (int p = gid; p < 64 * 32 * 64 * 8; p += stride) {   // Wh
        int e = p & 7, l = (p >> 3) & 63, kb = (p >> 9) & 31, jt = p >> 14;
        int j = jt * 16 + (l & 15);
        int k = kb * 32 + ((l >> 4) << 3) + e;
        u32 hi, lo; split2(Wh[k * HH + j], hi, lo);
        WhPh[p] = (u16)hi; WhPl[p] = (u16)lo;
    }
    for (int p = gid; p < NN * HH; p += stride) {            // h0 -> parity 1
        u32 hi, lo; split2(h0[p], hi, lo);
        int n = p >> 10, j = p & 1023;
        int gg = n >> 4, row = n & 15;
        int kb = j >> 5, c = j & 31;
        int lane_f = row | (((c >> 3) & 3) << 4);
        int e = c & 7;
        hpk[((4 + gg) * 32 + kb) * 512 + lane_f * 8 + e] = (hi << 16) | lo;
    }
}

// ---------------------------------------------------------------------------
// Phase 1: out = x@Wx + b   (split-bf16, 128x128 tiles, grid 2048) — proven
// ---------------------------------------------------------------------------
__global__ __launch_bounds__(256) void gemm_kernel(
    const float* __restrict__ x, const float* __restrict__ b,
    const u16* __restrict__ WxPh, const u16* __restrict__ WxPl,
    float* __restrict__ out)
{
    __shared__ __align__(16) u32 ldsA[2][128][20];

    const int tid = threadIdx.x;
    const int bid = blockIdx.x;
    const int w   = tid >> 6;
    const int l   = tid & 63;
    const int wm = w >> 1, wj = w & 1;

    const int m0 = (bid >> 3) * 128;
    const int jb = bid & 7;
    const int j0 = jb * 128;

    f32x4 acc[4][4] = {};
    for (int ks = 0; ks < 16; ++ks) {
        const int k0 = ks * 32;
        #pragma unroll
        for (int it = 0; it < 8; ++it) {
            int idx = it * 256 + tid;
            int m = idx >> 4, kp = idx & 15;
            float2 v = *(const float2*)(x + (m0 + m) * DD + k0 + kp * 2);
            u32 h0b, l0b, h1b, l1b;
            split2(v.x, h0b, l0b);
            split2(v.y, h1b, l1b);
            ldsA[0][m][kp] = h0b | (h1b << 16);
            ldsA[1][m][kp] = l0b | (l1b << 16);
        }
        __syncthreads();

        bf16x8 afh[4], afl[4], bfh[4], bfl[4];
        #pragma unroll
        for (int mt4 = 0; mt4 < 4; ++mt4) {
            int row = wm * 64 + mt4 * 16 + (l & 15);
            int co  = (l >> 4) * 4;
            afh[mt4] = *(const bf16x8*)&ldsA[0][row][co];
            afl[mt4] = *(const bf16x8*)&ldsA[1][row][co];
        }
        #pragma unroll
        for (int jt4 = 0; jt4 < 4; ++jt4) {
            int jtile = jb * 8 + wj * 4 + jt4;
            int off = ((jtile * 16 + ks) * 64 + l) * 8;
            bfh[jt4] = *(const bf16x8*)(WxPh + off);
            bfl[jt4] = *(const bf16x8*)(WxPl + off);
        }
        #pragma unroll
        for (int mt4 = 0; mt4 < 4; ++mt4)
            #pragma unroll
            for (int jt4 = 0; jt4 < 4; ++jt4) {
                acc[mt4][jt4] = MFMA16(afh[mt4], bfh[jt4], acc[mt4][jt4]);
                acc[mt4][jt4] = MFMA16(afh[mt4], bfl[jt4], acc[mt4][jt4]);
                acc[mt4][jt4] = MFMA16(afl[mt4], bfh[jt4], acc[mt4][jt4]);
            }
        __syncthreads();
    }
    #pragma unroll
    for (int jt4 = 0; jt4 < 4; ++jt4) {
        int j = j0 + wj * 64 + jt4 * 16 + (l & 15);
        float bj = b[j];
        #pragma unroll
        for (int mt4 = 0; mt4 < 4; ++mt4)
            #pragma unroll
            for (int r = 0; r < 4; ++r) {
                int m = m0 + wm * 64 + mt4 * 16 + (l >> 4) * 4 + r;
                out[m * HH + j] = acc[mt4][jt4][r] + bj;
            }
    }
}

// ---------------------------------------------------------------------------
// Phase 2: scan. Grid 128 x 256. Group g = bid&3 owns rows [16g,16g+16);
// block cb = bid>>2 owns cols [32cb,32cb+32); wave w owns k [256w,+256).
// Wh slice in LDS (128 KB). Flags: flags[g][cb*4+w'] = t+1 when wave w' of
// block cb has its rows of h_t AT THE IC (posted after vmcnt ack).
// Every wave polls all 128 group flags (data dep + WAR/lap safety), then
// fetches its h slice ONCE (dense frag-ordered reads, no validation).
// ---------------------------------------------------------------------------
__global__ __launch_bounds__(256, 1) void scan_kernel(
    const u16* __restrict__ WhPh, const u16* __restrict__ WhPl,
    u32* __restrict__ hbuf,          // [2][4][32][512] dwords, frag-ordered
    float* __restrict__ out, u32* __restrict__ flags)
{
    __shared__ __align__(16) char ldsWhH[65536];   // 64 frags x 1 KB
    __shared__ __align__(16) char ldsWhL[65536];
    __shared__ float ldsRed[2][4][16][34];

    const int tid = threadIdx.x;
    const int bid = blockIdx.x;
    const int g   = bid & 3;
    const int cb  = bid >> 2;
    const int w   = tid >> 6;
    const int l   = tid & 63;

    // ---- stage Wh fragments into LDS (once); frag f=(w*2+jj)*8+i ----
    for (int c = tid; c < 4096; c += 256) {        // 4096 x 16B chunks
        int f = c >> 6, q = c & 63;
        int fw = f >> 4, fj = (f >> 3) & 1, fi = f & 7;
        int src = (((cb * 2 + fj) * 32) + (fw * 8 + fi)) * 512 + q * 8;
        *(u32x4*)(ldsWhH + c * 16) = *(const u32x4*)(WhPh + src);
        *(u32x4*)(ldsWhL + c * 16) = *(const u32x4*)(WhPl + src);
    }
    __syncthreads();

    const int rF = tid >> 4;                       // row this thread finalizes
    const int nF = g * 16 + rF;
    const int c0 = (tid & 15) * 2;                 // col pair within 32
    const int jE = cb * 32 + c0;

    // producer store slot (frag order): kb = cb, lane_f, e (+ parity base)
    const int lane_f = rF | (((c0 >> 3) & 3) << 4);
    const int eP     = c0 & 7;
    const int pOff   = (g * 32 + cb) * 512 + lane_f * 8 + eP;

    // consumer fetch base (frag order): kb = w*8 + i, my lane's 8 dwords
    const int cOff   = (g * 32 + w * 8) * 512 + l * 8;

    u32* gf = flags + g * 512;                     // 128 flags x 4-dword stride
    u32* fp0 = gf + l * 4;
    u32* fp1 = gf + (l + 64) * 4;

    float2 xw = *(const float2*)&out[(nF * TT) * HH + jE];

    for (int t = 0; t < TT; ++t) {
        // ---- Wh fragment LDS reads (issued; consumed in MFMA) ----
        u32x4 bh[2][8], bl[2][8];
        #pragma unroll
        for (int jj = 0; jj < 2; ++jj)
            #pragma unroll
            for (int i = 0; i < 8; ++i) {
                int off = (((w * 2 + jj) * 8 + i) << 10) + (l << 4);
                bh[jj][i] = *(const u32x4*)(ldsWhH + off);
                bl[jj][i] = *(const u32x4*)(ldsWhL + off);
            }
        __builtin_amdgcn_sched_barrier(0);

        // ---- poll flags: all 128 producer-waves of the group at >= t ----
        if (t > 0) {
            const u32 tgt = (u32)t;
            while (true) {
                u32 f0, f1;
                asm volatile("global_load_dword %0, %2, off sc0 sc1\n\t"
                             "global_load_dword %1, %3, off sc0 sc1\n\t"
                             "s_waitcnt vmcnt(0)"
                             : "=&v"(f0), "=&v"(f1) : "v"(fp0), "v"(fp1));
                if (__ballot((f0 >= tgt) && (f1 >= tgt)) == ~0ull) break;
            }
        }
        __builtin_amdgcn_sched_barrier(0);

        // ---- fetch h_{t-1} once (dense, frag-ordered) ----
        const u32* hp = hbuf + ((t - 1) & 1) * 4 * 32 * 512 + cOff;
        u32x4 a0[8], a1[8];
        #pragma unroll
        for (int i = 0; i < 8; ++i) {
            a0[i] = ld16_sys(hp + i * 512);
            a1[i] = ld16_sys(hp + i * 512 + 4);
        }
        wait_vm0();
        __builtin_amdgcn_sched_barrier(0);         // rule-18 fence
        #pragma unroll
        for (int i = 0; i < 8; ++i) {
            asm volatile("" : "+v"(a0[i]));
            asm volatile("" : "+v"(a1[i]));
        }

        // ---- unpack h + MFMA (3 split chains) ----
        f32x4 ahh[2] = {}, ahl[2] = {}, alh[2] = {};
        #pragma unroll
        for (int i = 0; i < 8; ++i) {
            bf16x8 Ah, Al;
            #pragma unroll
            for (int e = 0; e < 4; ++e) {
                u32 u0 = a0[i][e], u1 = a1[i][e];
                Ah[e]     = (short)(u0 >> 16);
                Al[e]     = (short)(u0 & 0xFFFFu);
                Ah[4 + e] = (short)(u1 >> 16);
                Al[4 + e] = (short)(u1 & 0xFFFFu);
            }
            #pragma unroll
            for (int jj = 0; jj < 2; ++jj) {
                bf16x8 Bh = __builtin_bit_cast(bf16x8, bh[jj][i]);
                bf16x8 Bl = __builtin_bit_cast(bf16x8, bl[jj][i]);
                ahh[jj] = MFMA16(Ah, Bh, ahh[jj]);
                ahl[jj] = MFMA16(Ah, Bl, ahl[jj]);
                alh[jj] = MFMA16(Al, Bh, alh[jj]);
            }
        }

        // ---- cross-wave reduce (double-buffered, 1 barrier) ----
        const int par = t & 1;
        {
            int rb = (l >> 4) * 4, cc = l & 15;
            #pragma unroll
            for (int jj = 0; jj < 2; ++jj) {
                f32x4 s4 = ahh[jj] + ahl[jj] + alh[jj];
                #pragma unroll
                for (int e = 0; e < 4; ++e)
                    ldsRed[par][w][rb + e][jj * 16 + cc] = s4[e];
            }
        }
        __syncthreads();

        float sx = 0.f, sy = 0.f;
        #pragma unroll
        for (int wq = 0; wq < 4; ++wq) {
            float2 v = *(const float2*)&ldsRed[par][wq][rF][c0];
            sx += v.x; sy += v.y;
        }
        float hv0 = fast_tanh(xw.x + sx);
        float hv1 = fast_tanh(xw.y + sy);

        if (t + 1 < TT) {
            // post h_t (wire = hi<<16 | lo, frag-ordered), ack, then flag
            u32 hb0, lb0, hb1, lb1;
            split2(hv0, hb0, lb0);
            split2(hv1, hb1, lb1);
            st8_sys(hbuf + par * 4 * 32 * 512 + pOff,
                    (hb0 << 16) | lb0, (hb1 << 16) | lb1);
            wait_vm0();                            // this wave's posts at IC
            if (l == 0) st_flag(gf + (cb * 4 + w) * 4, (u32)(t + 1));
        }
        *(float2*)&out[(nF * TT + t) * HH + jE] = make_float2(hv0, hv1);
        if (t + 1 < TT)
            xw = *(const float2*)&out[(nF * TT + t + 1) * HH + jE];
    }
}

// ---------------------------------------------------------------------------
extern "C" void kernel_launch(void* const* d_in, const int* in_sizes, int n_in,
                              void* d_out, int out_size, void* d_ws, size_t ws_size,
                              hipStream_t stream) {
    const float* x  = (const float*)d_in[0];
    const float* h0 = (const float*)d_in[1];
    const float* Wx = (const float*)d_in[2];
    const float* Wh = (const float*)d_in[3];
    const float* b  = (const float*)d_in[4];
    float* out = (float*)d_out;

    char* ws = (char*)d_ws;
    u16* WxPh = (u16*)(ws);                           // 1 MB
    u16* WxPl = (u16*)(ws + (1u << 20));              // 1 MB
    u16* WhPh = (u16*)(ws + (2u << 20));              // 2 MB
    u16* WhPl = (u16*)(ws + (4u << 20));              // 2 MB
    u32* hbuf = (u32*)(ws + (6u << 20));              // [2][4][32][512] = 512 KB
    u32* flags= (u32*)(ws + (6u << 20) + (1u << 19)); // 4 x 512 u32 = 8 KB

    hipMemsetAsync(flags, 0, 4 * 512 * sizeof(u32), stream);
    prep_kernel<<<2048, 256, 0, stream>>>(Wx, Wh, h0, WxPh, WxPl, WhPh, WhPl, hbuf);
    gemm_kernel<<<2048, 256, 0, stream>>>(x, b, WxPh, WxPl, out);
    scan_kernel<<<128, 256, 0, stream>>>(WhPh, WhPl, hbuf, out, flags);
}